// Round 9
// baseline (686.973 us; speedup 1.0000x reference)
//
#include <hip/hip_runtime.h>
#include <hip/hip_bf16.h>
#include <math.h>

// HelicalGNNFrontend: 2-layer GATv2 (heads=1, self-loops, mean loop edge_attr)
// N=50000, E=800000, NODE_DIM=HID=128, EDGE_DIM=32.
//
// Round 9: drop the ea permute (R8 scatter moved 205 MB of random ea rows).
// An ea row == one 128B cache line, and the fused kernel reads rows on the
// SCALAR pipe -> random row reads cost the same line fetch as streaming.
// Scatter now emits only int2{src, edge_id} (6.4 MB); fused indexes
// ea + eid*32 directly (wave-uniform -> s_load). ea becomes L3-resident
// for layer 2. Everything else frozen from R8 (1-wave wg, 2-wide pipeline,
// scalar ea path, composed layer-1 weights, self-loop-last, defer-max).

#define HIP_N 50000
#define HIP_E 800000
#define HIP_H 128
#define HIP_ED 32
#define NEG_SLOPE 0.2f
#define RESCALE_THR 8.0f

// ---------------- edge-index dtype detection ----------------
__global__ void k_detect(const int* __restrict__ ei, int* __restrict__ is32) {
    int j = blockIdx.x * blockDim.x + threadIdx.x;   // j in [0, 4096)
    if (j < 4096) {
        if (ei[2 * j + 1] != 0) atomicOr(is32, 1);
    }
}

__device__ __forceinline__ int fetch_idx(const int* __restrict__ ei, int is32, long long pos) {
    return is32 ? ei[pos] : ei[2 * pos];  // little-endian low word for int64
}

// ---------------- CSR build ----------------
__global__ void k_hist(const int* __restrict__ ei, const int* __restrict__ flag,
                       int* __restrict__ deg) {
    int is32 = *flag;
    int e = blockIdx.x * blockDim.x + threadIdx.x;
    if (e < HIP_E) {
        int d = fetch_idx(ei, is32, (long long)HIP_E + e);
        atomicAdd(&deg[d], 1);
    }
}

#define SCAN_TILE 1024
#define SCAN_NB ((HIP_N + SCAN_TILE - 1) / SCAN_TILE)   // 49

__global__ __launch_bounds__(256) void k_scan1(const int* __restrict__ deg,
                                               int* __restrict__ bsums) {
    __shared__ int ws[4];
    int b = blockIdx.x, t = threadIdx.x;
    int base = b * SCAN_TILE;
    int v = 0;
#pragma unroll
    for (int j = 0; j < 4; ++j) {
        int i = base + t + 256 * j;
        if (i < HIP_N) v += deg[i];
    }
#pragma unroll
    for (int off = 32; off > 0; off >>= 1) v += __shfl_xor(v, off);
    int lane = t & 63, wid = t >> 6;
    if (lane == 0) ws[wid] = v;
    __syncthreads();
    if (t == 0) bsums[b] = ws[0] + ws[1] + ws[2] + ws[3];
}

__global__ __launch_bounds__(64) void k_scan2(const int* __restrict__ bsums,
                                              int* __restrict__ bscan) {
    int t = threadIdx.x;
    int v = (t < SCAN_NB) ? bsums[t] : 0;
    int incl = v;
#pragma unroll
    for (int off = 1; off < 64; off <<= 1) {
        int u = __shfl_up(incl, off);
        if (t >= off) incl += u;
    }
    if (t < SCAN_NB) bscan[t] = incl - v;   // exclusive
}

__global__ __launch_bounds__(1024) void k_scan3(const int* __restrict__ deg,
                                                const int* __restrict__ bscan,
                                                int* __restrict__ offs,
                                                int* __restrict__ cursor) {
    __shared__ int wsum[16];
    int b = blockIdx.x, t = threadIdx.x;
    int i = b * SCAN_TILE + t;
    int lane = t & 63, wid = t >> 6;
    int v = (i < HIP_N) ? deg[i] : 0;
    int incl = v;
#pragma unroll
    for (int off = 1; off < 64; off <<= 1) {
        int u = __shfl_up(incl, off);
        if (lane >= off) incl += u;
    }
    if (lane == 63) wsum[wid] = incl;
    __syncthreads();
    if (wid == 0 && lane < 16) {
        int w = wsum[lane];
#pragma unroll
        for (int off = 1; off < 16; off <<= 1) {
            int u = __shfl_up(w, off);
            if (lane >= off) w += u;
        }
        wsum[lane] = w;   // inclusive over waves
    }
    __syncthreads();
    int baseadd = bscan[b] + (wid > 0 ? wsum[wid - 1] : 0);
    int excl = baseadd + incl - v;
    if (i < HIP_N) {
        offs[i] = excl;
        cursor[i] = excl;
        if (i == HIP_N - 1) offs[HIP_N] = excl + v;
    }
}

// scatter: se[pos] = {src, edge_id}  (8B random write; no ea copy)
__global__ void k_scatter(const int* __restrict__ ei, const int* __restrict__ flag,
                          int* __restrict__ cursor, int2* __restrict__ se) {
    int is32 = *flag;
    int e = blockIdx.x * blockDim.x + threadIdx.x;
    if (e < HIP_E) {
        int s = fetch_idx(ei, is32, e);
        int d = fetch_idx(ei, is32, (long long)HIP_E + e);
        int pos = atomicAdd(&cursor[d], 1);
        se[pos] = make_int2(s, e);
    }
}

// ---------------- weight composition (folds k_emb into layer-1) ----------------
// Wlf = W_emb@Wl1, blf = b_emb@Wl1 + bl1, Wrf = W_emb@Wr1, brf = b_emb@Wr1
__global__ __launch_bounds__(128) void k_compose(
    const float* __restrict__ Wemb, const float* __restrict__ bemb,
    const float* __restrict__ Wl, const float* __restrict__ bl,
    const float* __restrict__ Wr,
    float* __restrict__ Wlf, float* __restrict__ blf,
    float* __restrict__ Wrf, float* __restrict__ brf,
    float* __restrict__ zerob) {
    int b = blockIdx.x, c = threadIdx.x;
    if (b < 128) {
        float acc = 0.f;
        for (int k = 0; k < 128; ++k) acc += Wemb[b * 128 + k] * Wl[k * 128 + c];
        Wlf[b * 128 + c] = acc;
    } else if (b < 256) {
        int r = b - 128;
        float acc = 0.f;
        for (int k = 0; k < 128; ++k) acc += Wemb[r * 128 + k] * Wr[k * 128 + c];
        Wrf[r * 128 + c] = acc;
    } else if (b == 256) {
        float acc = bl[c];
        for (int k = 0; k < 128; ++k) acc += bemb[k] * Wl[k * 128 + c];
        blf[c] = acc;
    } else {
        float acc = 0.f;
        for (int k = 0; k < 128; ++k) acc += bemb[k] * Wr[k * 128 + c];
        brf[c] = acc;
        zerob[c] = 0.f;
    }
}

// ---------------- dual GEMM (fp32, LDS-tiled, 32 rows/block) ----------------
// xl = h@Wl + bl ; xr = h@Wr + br
__global__ __launch_bounds__(256) void k_lin(const float* __restrict__ h,
                                             const float* __restrict__ Wl,
                                             const float* __restrict__ bl,
                                             const float* __restrict__ Wr,
                                             const float* __restrict__ br,
                                             float* __restrict__ xl,
                                             float* __restrict__ xr, int n) {
    __shared__ float tile[32][128];
    int rb = blockIdx.x * 32;
    int tid = threadIdx.x;
    for (int j = 0; j < 16; ++j) {
        int idx = j * 256 + tid;
        int r = idx >> 7, c = idx & 127;
        int row = rb + r;
        tile[r][c] = (row < n) ? h[(size_t)row * 128 + c] : 0.f;
    }
    __syncthreads();
    int c = tid & 127, g = tid >> 7;
    float accl[16], accr[16];
#pragma unroll
    for (int r = 0; r < 16; ++r) { accl[r] = 0.f; accr[r] = 0.f; }
    for (int d4 = 0; d4 < 32; ++d4) {
        int d = d4 * 4;
        float wl0 = Wl[(d + 0) * 128 + c];
        float wl1 = Wl[(d + 1) * 128 + c];
        float wl2 = Wl[(d + 2) * 128 + c];
        float wl3 = Wl[(d + 3) * 128 + c];
        float wr0 = Wr[(d + 0) * 128 + c];
        float wr1 = Wr[(d + 1) * 128 + c];
        float wr2 = Wr[(d + 2) * 128 + c];
        float wr3 = Wr[(d + 3) * 128 + c];
#pragma unroll
        for (int r = 0; r < 16; ++r) {
            const float4 hv = *(const float4*)&tile[g * 16 + r][d];
            accl[r] += hv.x * wl0 + hv.y * wl1 + hv.z * wl2 + hv.w * wl3;
            accr[r] += hv.x * wr0 + hv.y * wr1 + hv.z * wr2 + hv.w * wr3;
        }
    }
    float bbl = bl[c], bbr = br[c];
    for (int r = 0; r < 16; ++r) {
        int row = rb + g * 16 + r;
        if (row < n) {
            xl[(size_t)row * 128 + c] = accl[r] + bbl;
            xr[(size_t)row * 128 + c] = accr[r] + bbr;
        }
    }
}

// ---------------- fused per-node online softmax + aggregation ----------------
// ONE 64-thread block per node (i = blockIdx.x): all per-edge addresses are
// wave-uniform -> scalar s_load path; only the xl gather uses vector memory.
// ea rows read in ORIGINAL order via eid indirection (row == one cache line).
// 2-wide edge pipeline: pair-ahead gather prefetch, interleaved shfl chains.
__global__ __launch_bounds__(64) void k_node_fused(
    const int* __restrict__ offs, const int2* __restrict__ se,
    const float* __restrict__ ea,
    const float* __restrict__ We, const float* __restrict__ att,
    const float* __restrict__ xl, const float* __restrict__ xr,
    const float* __restrict__ bo, float* __restrict__ hout) {
    int i = blockIdx.x;           // uniform node id
    int t = threadIdx.x;          // lane, owns feature dims (2t, 2t+1)

    const float2* We2 = (const float2*)We;
    float2 w00 = We2[ 0*64+t], w01 = We2[ 1*64+t], w02 = We2[ 2*64+t], w03 = We2[ 3*64+t];
    float2 w04 = We2[ 4*64+t], w05 = We2[ 5*64+t], w06 = We2[ 6*64+t], w07 = We2[ 7*64+t];
    float2 w08 = We2[ 8*64+t], w09 = We2[ 9*64+t], w10 = We2[10*64+t], w11 = We2[11*64+t];
    float2 w12 = We2[12*64+t], w13 = We2[13*64+t], w14 = We2[14*64+t], w15 = We2[15*64+t];
    float2 w16 = We2[16*64+t], w17 = We2[17*64+t], w18 = We2[18*64+t], w19 = We2[19*64+t];
    float2 w20 = We2[20*64+t], w21 = We2[21*64+t], w22 = We2[22*64+t], w23 = We2[23*64+t];
    float2 w24 = We2[24*64+t], w25 = We2[25*64+t], w26 = We2[26*64+t], w27 = We2[27*64+t];
    float2 w28 = We2[28*64+t], w29 = We2[29*64+t], w30 = We2[30*64+t], w31 = We2[31*64+t];

    float2 attv = ((const float2*)att)[t];
    float2 bov  = ((const float2*)bo)[t];
    float2 xri  = ((const float2*)(xr + (size_t)i * HIP_H))[t];
    float2 xli  = ((const float2*)(xl + (size_t)i * HIP_H))[t];

    float m = -1e30f;
    float denom = 0.f;
    float accx = 0.f, accy = 0.f;
    float epsx = 0.f, epsy = 0.f;   // sum of per-edge eproj (for self-loop)

    int o0 = offs[i], o1 = offs[i + 1];     // uniform -> s_load
    int cnt = o1 - o0;
    int pairs = cnt >> 1;
    const float2* xl2 = (const float2*)xl;

#define ACC4(EX, EY, A, C0, C1, C2, C3)                               \
    EX += A.x * C0.x + A.y * C1.x + A.z * C2.x + A.w * C3.x;          \
    EY += A.x * C0.y + A.y * C1.y + A.z * C2.y + A.w * C3.y;

#define EPROJ(EX, EY, P)                                              \
    {                                                                 \
        float4 a0 = (P)[0], a1 = (P)[1], a2 = (P)[2], a3 = (P)[3];    \
        float4 a4 = (P)[4], a5 = (P)[5], a6 = (P)[6], a7 = (P)[7];    \
        ACC4(EX, EY, a0, w00, w01, w02, w03)                          \
        ACC4(EX, EY, a1, w04, w05, w06, w07)                          \
        ACC4(EX, EY, a2, w08, w09, w10, w11)                          \
        ACC4(EX, EY, a3, w12, w13, w14, w15)                          \
        ACC4(EX, EY, a4, w16, w17, w18, w19)                          \
        ACC4(EX, EY, a5, w20, w21, w22, w23)                          \
        ACC4(EX, EY, a6, w24, w25, w26, w27)                          \
        ACC4(EX, EY, a7, w28, w29, w30, w31)                          \
    }

    // pair-ahead prefetch: current pair (src,eid) + the two xl gathers
    int2 c0 = make_int2(0, 0), c1 = make_int2(0, 0);
    float2 xA = make_float2(0.f, 0.f), xB = make_float2(0.f, 0.f);
    if (pairs > 0) {
        c0 = se[o0];                        // uniform -> s_load
        c1 = se[o0 + 1];
        xA = xl2[(size_t)c0.x * 64 + t];
        xB = xl2[(size_t)c1.x * 64 + t];
    }

    for (int pp = 0; pp < pairs; ++pp) {
        int e = o0 + 2 * pp;
        float2 x0 = xA, x1 = xB;
        int eid0 = c0.y, eid1 = c1.y;
        if (pp + 1 < pairs) {               // prefetch next pair
            c0 = se[e + 2];
            c1 = se[e + 3];
            xA = xl2[(size_t)c0.x * 64 + t];
            xB = xl2[(size_t)c1.x * 64 + t];
        }
        const float4* p0r = (const float4*)(ea + (size_t)eid0 * HIP_ED);  // uniform
        const float4* p1r = (const float4*)(ea + (size_t)eid1 * HIP_ED);
        float ex0 = 0.f, ey0 = 0.f, ex1 = 0.f, ey1 = 0.f;
        EPROJ(ex0, ey0, p0r)
        EPROJ(ex1, ey1, p1r)
        epsx += ex0 + ex1; epsy += ey0 + ey1;
        float vx0 = x0.x + xri.x + ex0, vy0 = x0.y + xri.y + ey0;
        float vx1 = x1.x + xri.x + ex1, vy1 = x1.y + xri.y + ey1;
        vx0 = vx0 > 0.f ? vx0 : NEG_SLOPE * vx0;
        vy0 = vy0 > 0.f ? vy0 : NEG_SLOPE * vy0;
        vx1 = vx1 > 0.f ? vx1 : NEG_SLOPE * vx1;
        vy1 = vy1 > 0.f ? vy1 : NEG_SLOPE * vy1;
        float p0 = vx0 * attv.x + vy0 * attv.y;
        float p1 = vx1 * attv.x + vy1 * attv.y;
#pragma unroll
        for (int off = 32; off > 0; off >>= 1) {   // interleaved chains
            p0 += __shfl_xor(p0, off);
            p1 += __shfl_xor(p1, off);
        }
        float pm = fmaxf(p0, p1);
        if (pm > m + RESCALE_THR) {         // defer-max rescale (wave-uniform)
            float sc = __expf(m - pm);
            accx *= sc; accy *= sc; denom *= sc;
            m = pm;
        }
        float wA = __expf(p0 - m);
        float wB = __expf(p1 - m);
        accx += wA * x0.x + wB * x1.x;
        accy += wA * x0.y + wB * x1.y;
        denom += wA + wB;
    }

    if (cnt & 1) {                          // tail edge
        int2 ct = se[o1 - 1];
        float2 x0 = xl2[(size_t)ct.x * 64 + t];
        const float4* pt = (const float4*)(ea + (size_t)ct.y * HIP_ED);
        float ex = 0.f, ey = 0.f;
        EPROJ(ex, ey, pt)
        epsx += ex; epsy += ey;
        float vx = x0.x + xri.x + ex;
        float vy = x0.y + xri.y + ey;
        vx = vx > 0.f ? vx : NEG_SLOPE * vx;
        vy = vy > 0.f ? vy : NEG_SLOPE * vy;
        float p = vx * attv.x + vy * attv.y;
#pragma unroll
        for (int off = 32; off > 0; off >>= 1) p += __shfl_xor(p, off);
        if (p > m + RESCALE_THR) {
            float sc = __expf(m - p);
            accx *= sc; accy *= sc; denom *= sc;
            m = p;
        }
        float w = __expf(p - m);
        accx += w * x0.x;
        accy += w * x0.y;
        denom += w;
    }
#undef EPROJ
#undef ACC4

    // ---- self-loop (last): loop_attr projection = mean of eproj ----
    float invdeg = 1.f / fmaxf((float)cnt, 1.f);
    float sx = xli.x + xri.x + epsx * invdeg;
    float sy = xli.y + xri.y + epsy * invdeg;
    sx = sx > 0.f ? sx : NEG_SLOPE * sx;
    sy = sy > 0.f ? sy : NEG_SLOPE * sy;
    float ps = sx * attv.x + sy * attv.y;
#pragma unroll
    for (int off = 32; off > 0; off >>= 1) ps += __shfl_xor(ps, off);

    float mm = fmaxf(m, ps);
    float wf = __expf(m - mm);
    float ws = __expf(ps - mm);
    denom = denom * wf + ws;
    accx = accx * wf + ws * xli.x;
    accy = accy * wf + ws * xli.y;

    float ox = accx / denom + bov.x;
    float oy = accy / denom + bov.y;
    float2 o;
    o.x = ox / (1.f + __expf(-ox));
    o.y = oy / (1.f + __expf(-oy));
    ((float2*)(hout + (size_t)i * HIP_H))[t] = o;
}

// ---------------- host launch ----------------
extern "C" void kernel_launch(void* const* d_in, const int* in_sizes, int n_in,
                              void* d_out, int out_size, void* d_ws, size_t ws_size,
                              hipStream_t stream) {
    const float* x      = (const float*)d_in[0];
    const int*   ei     = (const int*)d_in[1];
    const float* ea     = (const float*)d_in[2];
    const float* W_emb  = (const float*)d_in[3];
    const float* b_emb  = (const float*)d_in[4];
    const float* Wl1    = (const float*)d_in[5];
    const float* bl1    = (const float*)d_in[6];
    const float* Wr1    = (const float*)d_in[7];
    const float* We1    = (const float*)d_in[8];
    const float* att1   = (const float*)d_in[9];
    const float* bo1    = (const float*)d_in[10];
    const float* Wl2    = (const float*)d_in[11];
    const float* bl2    = (const float*)d_in[12];
    const float* Wr2    = (const float*)d_in[13];
    const float* We2    = (const float*)d_in[14];
    const float* att2   = (const float*)d_in[15];
    const float* bo2    = (const float*)d_in[16];
    float* out = (float*)d_out;

    char* p = (char*)d_ws;
    auto carve = [&](size_t bytes) {
        void* q = (void*)p;
        p += (bytes + 255) / 256 * 256;
        return q;
    };
    float* h        = (float*)carve((size_t)HIP_N * 128 * 4);
    float* xl       = (float*)carve((size_t)HIP_N * 128 * 4);
    float* xr       = (float*)carve((size_t)HIP_N * 128 * 4);
    int2*  se       = (int2*)carve((size_t)HIP_E * 8);
    int*   deg      = (int*)carve((size_t)HIP_N * 4);
    int*   offs     = (int*)carve((size_t)(HIP_N + 1) * 4);
    int*   cursor   = (int*)carve((size_t)HIP_N * 4);
    int*   flag     = (int*)carve(256);
    int*   bsums    = (int*)carve((size_t)SCAN_NB * 4);
    int*   bscan    = (int*)carve((size_t)SCAN_NB * 4);
    float* Wl1f     = (float*)carve(128 * 128 * 4);
    float* Wr1f     = (float*)carve(128 * 128 * 4);
    float* bl1f     = (float*)carve(128 * 4);
    float* br1f     = (float*)carve(128 * 4);
    float* zerob    = (float*)carve(128 * 4);

    hipMemsetAsync(deg, 0, (size_t)HIP_N * 4, stream);
    hipMemsetAsync(flag, 0, 4, stream);

    k_detect<<<16, 256, 0, stream>>>(ei, flag);
    k_hist<<<(HIP_E + 255) / 256, 256, 0, stream>>>(ei, flag, deg);
    k_scan1<<<SCAN_NB, 256, 0, stream>>>(deg, bsums);
    k_scan2<<<1, 64, 0, stream>>>(bsums, bscan);
    k_scan3<<<SCAN_NB, 1024, 0, stream>>>(deg, bscan, offs, cursor);
    k_scatter<<<(HIP_E + 255) / 256, 256, 0, stream>>>(ei, flag, cursor, se);
    k_compose<<<258, 128, 0, stream>>>(W_emb, b_emb, Wl1, bl1, Wr1,
                                       Wl1f, bl1f, Wr1f, br1f, zerob);

    int gemm_grid = (HIP_N + 31) / 32;
    // ----- layer 1 (embedding folded into composed weights) -----
    k_lin<<<gemm_grid, 256, 0, stream>>>(x, Wl1f, bl1f, Wr1f, br1f, xl, xr, HIP_N);
    k_node_fused<<<HIP_N, 64, 0, stream>>>(offs, se, ea, We1, att1,
                                           xl, xr, bo1, h);
    // ----- layer 2 -----
    k_lin<<<gemm_grid, 256, 0, stream>>>(h, Wl2, bl2, Wr2, zerob, xl, xr, HIP_N);
    k_node_fused<<<HIP_N, 64, 0, stream>>>(offs, se, ea, We2, att2,
                                           xl, xr, bo2, out);
}

// Round 10
// 609.188 us; speedup vs baseline: 1.1277x; 1.1277x over previous
//
#include <hip/hip_runtime.h>
#include <hip/hip_bf16.h>
#include <math.h>

// HelicalGNNFrontend: 2-layer GATv2 (heads=1, self-loops, mean loop edge_attr)
// N=50000, E=800000, NODE_DIM=HID=128, EDGE_DIM=32.
//
// Round 10: revert R9 (random scalar ea reads stalled SMEM queue; permuted
// ea_s restored). New: __launch_bounds__(64,4) on fused (VGPR budget 128 at
// zero occupancy cost since 1-wave workgroups are wg/CU-capped -> We truly
// register-resident), 3-wide edge pipeline, and fat-kernel fusion of
// scatter + layer-1 lin (independent work, overlapped in one dispatch).

#define HIP_N 50000
#define HIP_E 800000
#define HIP_H 128
#define HIP_ED 32
#define NEG_SLOPE 0.2f
#define RESCALE_THR 8.0f
#define LINB ((HIP_N + 31) / 32)          // 1563 lin blocks
#define SCATB ((HIP_E + 255) / 256)       // 3125 scatter blocks

// ---------------- edge-index dtype detection ----------------
__global__ void k_detect(const int* __restrict__ ei, int* __restrict__ is32) {
    int j = blockIdx.x * blockDim.x + threadIdx.x;   // j in [0, 4096)
    if (j < 4096) {
        if (ei[2 * j + 1] != 0) atomicOr(is32, 1);
    }
}

__device__ __forceinline__ int fetch_idx(const int* __restrict__ ei, int is32, long long pos) {
    return is32 ? ei[pos] : ei[2 * pos];  // little-endian low word for int64
}

// ---------------- CSR build ----------------
__global__ void k_hist(const int* __restrict__ ei, const int* __restrict__ flag,
                       int* __restrict__ deg) {
    int is32 = *flag;
    int e = blockIdx.x * blockDim.x + threadIdx.x;
    if (e < HIP_E) {
        int d = fetch_idx(ei, is32, (long long)HIP_E + e);
        atomicAdd(&deg[d], 1);
    }
}

#define SCAN_TILE 1024
#define SCAN_NB ((HIP_N + SCAN_TILE - 1) / SCAN_TILE)   // 49

__global__ __launch_bounds__(256) void k_scan1(const int* __restrict__ deg,
                                               int* __restrict__ bsums) {
    __shared__ int ws[4];
    int b = blockIdx.x, t = threadIdx.x;
    int base = b * SCAN_TILE;
    int v = 0;
#pragma unroll
    for (int j = 0; j < 4; ++j) {
        int i = base + t + 256 * j;
        if (i < HIP_N) v += deg[i];
    }
#pragma unroll
    for (int off = 32; off > 0; off >>= 1) v += __shfl_xor(v, off);
    int lane = t & 63, wid = t >> 6;
    if (lane == 0) ws[wid] = v;
    __syncthreads();
    if (t == 0) bsums[b] = ws[0] + ws[1] + ws[2] + ws[3];
}

__global__ __launch_bounds__(64) void k_scan2(const int* __restrict__ bsums,
                                              int* __restrict__ bscan) {
    int t = threadIdx.x;
    int v = (t < SCAN_NB) ? bsums[t] : 0;
    int incl = v;
#pragma unroll
    for (int off = 1; off < 64; off <<= 1) {
        int u = __shfl_up(incl, off);
        if (t >= off) incl += u;
    }
    if (t < SCAN_NB) bscan[t] = incl - v;   // exclusive
}

__global__ __launch_bounds__(1024) void k_scan3(const int* __restrict__ deg,
                                                const int* __restrict__ bscan,
                                                int* __restrict__ offs,
                                                int* __restrict__ cursor) {
    __shared__ int wsum[16];
    int b = blockIdx.x, t = threadIdx.x;
    int i = b * SCAN_TILE + t;
    int lane = t & 63, wid = t >> 6;
    int v = (i < HIP_N) ? deg[i] : 0;
    int incl = v;
#pragma unroll
    for (int off = 1; off < 64; off <<= 1) {
        int u = __shfl_up(incl, off);
        if (lane >= off) incl += u;
    }
    if (lane == 63) wsum[wid] = incl;
    __syncthreads();
    if (wid == 0 && lane < 16) {
        int w = wsum[lane];
#pragma unroll
        for (int off = 1; off < 16; off <<= 1) {
            int u = __shfl_up(w, off);
            if (lane >= off) w += u;
        }
        wsum[lane] = w;   // inclusive over waves
    }
    __syncthreads();
    int baseadd = bscan[b] + (wid > 0 ? wsum[wid - 1] : 0);
    int excl = baseadd + incl - v;
    if (i < HIP_N) {
        offs[i] = excl;
        cursor[i] = excl;
        if (i == HIP_N - 1) offs[HIP_N] = excl + v;
    }
}

// ---------------- shared bodies ----------------
// dual GEMM body: xl = h@Wl + bl ; xr = h@Wr + br (one 32-row tile per call)
__device__ __forceinline__ void lin_body(const float* __restrict__ h,
                                         const float* __restrict__ Wl,
                                         const float* __restrict__ bl,
                                         const float* __restrict__ Wr,
                                         const float* __restrict__ br,
                                         float* __restrict__ xl,
                                         float* __restrict__ xr, int n, int blk) {
    __shared__ float tile[32][128];
    int rb = blk * 32;
    int tid = threadIdx.x;
    for (int j = 0; j < 16; ++j) {
        int idx = j * 256 + tid;
        int r = idx >> 7, c = idx & 127;
        int row = rb + r;
        tile[r][c] = (row < n) ? h[(size_t)row * 128 + c] : 0.f;
    }
    __syncthreads();
    int c = tid & 127, g = tid >> 7;
    float accl[16], accr[16];
#pragma unroll
    for (int r = 0; r < 16; ++r) { accl[r] = 0.f; accr[r] = 0.f; }
    for (int d4 = 0; d4 < 32; ++d4) {
        int d = d4 * 4;
        float wl0 = Wl[(d + 0) * 128 + c];
        float wl1 = Wl[(d + 1) * 128 + c];
        float wl2 = Wl[(d + 2) * 128 + c];
        float wl3 = Wl[(d + 3) * 128 + c];
        float wr0 = Wr[(d + 0) * 128 + c];
        float wr1 = Wr[(d + 1) * 128 + c];
        float wr2 = Wr[(d + 2) * 128 + c];
        float wr3 = Wr[(d + 3) * 128 + c];
#pragma unroll
        for (int r = 0; r < 16; ++r) {
            const float4 hv = *(const float4*)&tile[g * 16 + r][d];
            accl[r] += hv.x * wl0 + hv.y * wl1 + hv.z * wl2 + hv.w * wl3;
            accr[r] += hv.x * wr0 + hv.y * wr1 + hv.z * wr2 + hv.w * wr3;
        }
    }
    float bbl = bl[c], bbr = br[c];
    for (int r = 0; r < 16; ++r) {
        int row = rb + g * 16 + r;
        if (row < n) {
            xl[(size_t)row * 128 + c] = accl[r] + bbl;
            xr[(size_t)row * 128 + c] = accr[r] + bbr;
        }
    }
}

// scatter body: e_src[pos]=src, ea_s[pos]=ea[e] (permuted rows, R8-proven)
__device__ __forceinline__ void scatter_body(const int* __restrict__ ei, int is32,
                                             int* __restrict__ cursor,
                                             int* __restrict__ e_src,
                                             const float* __restrict__ ea,
                                             float* __restrict__ ea_s, int e) {
    if (e < HIP_E) {
        int s = fetch_idx(ei, is32, e);
        int d = fetch_idx(ei, is32, (long long)HIP_E + e);
        int pos = atomicAdd(&cursor[d], 1);
        e_src[pos] = s;
        const float4* src4 = (const float4*)(ea + (size_t)e * HIP_ED);
        float4* dst4 = (float4*)(ea_s + (size_t)pos * HIP_ED);
#pragma unroll
        for (int q = 0; q < 8; ++q) dst4[q] = src4[q];
    }
}

// fat kernel: blocks [0, LINB) do layer-1 lin; blocks [LINB, LINB+SCATB) scatter
__global__ __launch_bounds__(256) void k_fat1(
    const float* __restrict__ x, const float* __restrict__ Wl,
    const float* __restrict__ bl, const float* __restrict__ Wr,
    const float* __restrict__ br, float* __restrict__ xl, float* __restrict__ xr,
    const int* __restrict__ ei, const int* __restrict__ flag,
    int* __restrict__ cursor, int* __restrict__ e_src,
    const float* __restrict__ ea, float* __restrict__ ea_s) {
    if (blockIdx.x < LINB) {
        lin_body(x, Wl, bl, Wr, br, xl, xr, HIP_N, blockIdx.x);
    } else {
        int e = (blockIdx.x - LINB) * 256 + threadIdx.x;
        scatter_body(ei, *flag, cursor, e_src, ea, ea_s, e);
    }
}

__global__ __launch_bounds__(256) void k_lin(const float* __restrict__ h,
                                             const float* __restrict__ Wl,
                                             const float* __restrict__ bl,
                                             const float* __restrict__ Wr,
                                             const float* __restrict__ br,
                                             float* __restrict__ xl,
                                             float* __restrict__ xr, int n) {
    lin_body(h, Wl, bl, Wr, br, xl, xr, n, blockIdx.x);
}

// ---------------- weight composition (folds k_emb into layer-1) ----------------
__global__ __launch_bounds__(128) void k_compose(
    const float* __restrict__ Wemb, const float* __restrict__ bemb,
    const float* __restrict__ Wl, const float* __restrict__ bl,
    const float* __restrict__ Wr,
    float* __restrict__ Wlf, float* __restrict__ blf,
    float* __restrict__ Wrf, float* __restrict__ brf,
    float* __restrict__ zerob) {
    int b = blockIdx.x, c = threadIdx.x;
    if (b < 128) {
        float acc = 0.f;
        for (int k = 0; k < 128; ++k) acc += Wemb[b * 128 + k] * Wl[k * 128 + c];
        Wlf[b * 128 + c] = acc;
    } else if (b < 256) {
        int r = b - 128;
        float acc = 0.f;
        for (int k = 0; k < 128; ++k) acc += Wemb[r * 128 + k] * Wr[k * 128 + c];
        Wrf[r * 128 + c] = acc;
    } else if (b == 256) {
        float acc = bl[c];
        for (int k = 0; k < 128; ++k) acc += bemb[k] * Wl[k * 128 + c];
        blf[c] = acc;
    } else {
        float acc = 0.f;
        for (int k = 0; k < 128; ++k) acc += bemb[k] * Wr[k * 128 + c];
        brf[c] = acc;
        zerob[c] = 0.f;
    }
}

// ---------------- fused per-node online softmax + aggregation ----------------
// ONE 64-thread block per node. All per-edge addresses wave-uniform -> scalar
// s_load path; only the xl gather on vector memory. __launch_bounds__(64,4):
// VGPR budget 128 (free: wg/CU cap binds first) so We stays register-resident.
// 3-wide edge pipeline: triple-ahead gather prefetch, interleaved shfl chains.
__global__ __launch_bounds__(64, 4) void k_node_fused(
    const int* __restrict__ offs, const int* __restrict__ e_src,
    const float* __restrict__ ea_s,
    const float* __restrict__ We, const float* __restrict__ att,
    const float* __restrict__ xl, const float* __restrict__ xr,
    const float* __restrict__ bo, float* __restrict__ hout) {
    int i = blockIdx.x;           // uniform node id
    int t = threadIdx.x;          // lane, owns feature dims (2t, 2t+1)

    const float2* We2 = (const float2*)We;
    float2 w00 = We2[ 0*64+t], w01 = We2[ 1*64+t], w02 = We2[ 2*64+t], w03 = We2[ 3*64+t];
    float2 w04 = We2[ 4*64+t], w05 = We2[ 5*64+t], w06 = We2[ 6*64+t], w07 = We2[ 7*64+t];
    float2 w08 = We2[ 8*64+t], w09 = We2[ 9*64+t], w10 = We2[10*64+t], w11 = We2[11*64+t];
    float2 w12 = We2[12*64+t], w13 = We2[13*64+t], w14 = We2[14*64+t], w15 = We2[15*64+t];
    float2 w16 = We2[16*64+t], w17 = We2[17*64+t], w18 = We2[18*64+t], w19 = We2[19*64+t];
    float2 w20 = We2[20*64+t], w21 = We2[21*64+t], w22 = We2[22*64+t], w23 = We2[23*64+t];
    float2 w24 = We2[24*64+t], w25 = We2[25*64+t], w26 = We2[26*64+t], w27 = We2[27*64+t];
    float2 w28 = We2[28*64+t], w29 = We2[29*64+t], w30 = We2[30*64+t], w31 = We2[31*64+t];

    float2 attv = ((const float2*)att)[t];
    float2 bov  = ((const float2*)bo)[t];
    float2 xri  = ((const float2*)(xr + (size_t)i * HIP_H))[t];
    float2 xli  = ((const float2*)(xl + (size_t)i * HIP_H))[t];

    float m = -1e30f;
    float denom = 0.f;
    float accx = 0.f, accy = 0.f;
    float epsx = 0.f, epsy = 0.f;   // sum of per-edge eproj (for self-loop)

    int o0 = offs[i], o1 = offs[i + 1];     // uniform -> s_load
    int cnt = o1 - o0;
    int trips = cnt / 3;
    const float2* xl2 = (const float2*)xl;

#define ACC4(EX, EY, A, C0, C1, C2, C3)                               \
    EX += A.x * C0.x + A.y * C1.x + A.z * C2.x + A.w * C3.x;          \
    EY += A.x * C0.y + A.y * C1.y + A.z * C2.y + A.w * C3.y;

#define EPROJ(EX, EY, P)                                              \
    {                                                                 \
        float4 a0 = (P)[0], a1 = (P)[1], a2 = (P)[2], a3 = (P)[3];    \
        float4 a4 = (P)[4], a5 = (P)[5], a6 = (P)[6], a7 = (P)[7];    \
        ACC4(EX, EY, a0, w00, w01, w02, w03)                          \
        ACC4(EX, EY, a1, w04, w05, w06, w07)                          \
        ACC4(EX, EY, a2, w08, w09, w10, w11)                          \
        ACC4(EX, EY, a3, w12, w13, w14, w15)                          \
        ACC4(EX, EY, a4, w16, w17, w18, w19)                          \
        ACC4(EX, EY, a5, w20, w21, w22, w23)                          \
        ACC4(EX, EY, a6, w24, w25, w26, w27)                          \
        ACC4(EX, EY, a7, w28, w29, w30, w31)                          \
    }

    // triple-ahead prefetch of the three xl gathers
    float2 xA = make_float2(0.f, 0.f), xB = xA, xC = xA;
    if (trips > 0) {
        int s0 = e_src[o0];                 // uniform -> s_load
        int s1 = e_src[o0 + 1];
        int s2 = e_src[o0 + 2];
        xA = xl2[(size_t)s0 * 64 + t];
        xB = xl2[(size_t)s1 * 64 + t];
        xC = xl2[(size_t)s2 * 64 + t];
    }

    for (int tp = 0; tp < trips; ++tp) {
        int e = o0 + 3 * tp;
        float2 x0 = xA, x1 = xB, x2 = xC;
        if (tp + 1 < trips) {               // prefetch next triple
            int s0 = e_src[e + 3];
            int s1 = e_src[e + 4];
            int s2 = e_src[e + 5];
            xA = xl2[(size_t)s0 * 64 + t];
            xB = xl2[(size_t)s1 * 64 + t];
            xC = xl2[(size_t)s2 * 64 + t];
        }
        const float4* ea4 = (const float4*)(ea_s + (size_t)e * HIP_ED);  // uniform
        float ex0 = 0.f, ey0 = 0.f, ex1 = 0.f, ey1 = 0.f, ex2 = 0.f, ey2 = 0.f;
        EPROJ(ex0, ey0, ea4)
        EPROJ(ex1, ey1, ea4 + 8)
        EPROJ(ex2, ey2, ea4 + 16)
        epsx += ex0 + ex1 + ex2; epsy += ey0 + ey1 + ey2;
        float vx0 = x0.x + xri.x + ex0, vy0 = x0.y + xri.y + ey0;
        float vx1 = x1.x + xri.x + ex1, vy1 = x1.y + xri.y + ey1;
        float vx2 = x2.x + xri.x + ex2, vy2 = x2.y + xri.y + ey2;
        vx0 = vx0 > 0.f ? vx0 : NEG_SLOPE * vx0;
        vy0 = vy0 > 0.f ? vy0 : NEG_SLOPE * vy0;
        vx1 = vx1 > 0.f ? vx1 : NEG_SLOPE * vx1;
        vy1 = vy1 > 0.f ? vy1 : NEG_SLOPE * vy1;
        vx2 = vx2 > 0.f ? vx2 : NEG_SLOPE * vx2;
        vy2 = vy2 > 0.f ? vy2 : NEG_SLOPE * vy2;
        float p0 = vx0 * attv.x + vy0 * attv.y;
        float p1 = vx1 * attv.x + vy1 * attv.y;
        float p2 = vx2 * attv.x + vy2 * attv.y;
#pragma unroll
        for (int off = 32; off > 0; off >>= 1) {   // interleaved chains
            p0 += __shfl_xor(p0, off);
            p1 += __shfl_xor(p1, off);
            p2 += __shfl_xor(p2, off);
        }
        float pm = fmaxf(fmaxf(p0, p1), p2);
        if (pm > m + RESCALE_THR) {         // defer-max rescale (wave-uniform)
            float sc = __expf(m - pm);
            accx *= sc; accy *= sc; denom *= sc;
            m = pm;
        }
        float wA = __expf(p0 - m);
        float wB = __expf(p1 - m);
        float wC = __expf(p2 - m);
        accx += wA * x0.x + wB * x1.x + wC * x2.x;
        accy += wA * x0.y + wB * x1.y + wC * x2.y;
        denom += wA + wB + wC;
    }

    for (int e = o0 + 3 * trips; e < o1; ++e) {     // tail (0..2 edges)
        int s = e_src[e];
        float2 x0 = xl2[(size_t)s * 64 + t];
        const float4* ea4 = (const float4*)(ea_s + (size_t)e * HIP_ED);
        float ex = 0.f, ey = 0.f;
        EPROJ(ex, ey, ea4)
        epsx += ex; epsy += ey;
        float vx = x0.x + xri.x + ex;
        float vy = x0.y + xri.y + ey;
        vx = vx > 0.f ? vx : NEG_SLOPE * vx;
        vy = vy > 0.f ? vy : NEG_SLOPE * vy;
        float p = vx * attv.x + vy * attv.y;
#pragma unroll
        for (int off = 32; off > 0; off >>= 1) p += __shfl_xor(p, off);
        if (p > m + RESCALE_THR) {
            float sc = __expf(m - p);
            accx *= sc; accy *= sc; denom *= sc;
            m = p;
        }
        float w = __expf(p - m);
        accx += w * x0.x;
        accy += w * x0.y;
        denom += w;
    }
#undef EPROJ
#undef ACC4

    // ---- self-loop (last): loop_attr projection = mean of eproj ----
    float invdeg = 1.f / fmaxf((float)cnt, 1.f);
    float sx = xli.x + xri.x + epsx * invdeg;
    float sy = xli.y + xri.y + epsy * invdeg;
    sx = sx > 0.f ? sx : NEG_SLOPE * sx;
    sy = sy > 0.f ? sy : NEG_SLOPE * sy;
    float ps = sx * attv.x + sy * attv.y;
#pragma unroll
    for (int off = 32; off > 0; off >>= 1) ps += __shfl_xor(ps, off);

    float mm = fmaxf(m, ps);
    float wf = __expf(m - mm);
    float ws = __expf(ps - mm);
    denom = denom * wf + ws;
    accx = accx * wf + ws * xli.x;
    accy = accy * wf + ws * xli.y;

    float ox = accx / denom + bov.x;
    float oy = accy / denom + bov.y;
    float2 o;
    o.x = ox / (1.f + __expf(-ox));
    o.y = oy / (1.f + __expf(-oy));
    ((float2*)(hout + (size_t)i * HIP_H))[t] = o;
}

// ---------------- host launch ----------------
extern "C" void kernel_launch(void* const* d_in, const int* in_sizes, int n_in,
                              void* d_out, int out_size, void* d_ws, size_t ws_size,
                              hipStream_t stream) {
    const float* x      = (const float*)d_in[0];
    const int*   ei     = (const int*)d_in[1];
    const float* ea     = (const float*)d_in[2];
    const float* W_emb  = (const float*)d_in[3];
    const float* b_emb  = (const float*)d_in[4];
    const float* Wl1    = (const float*)d_in[5];
    const float* bl1    = (const float*)d_in[6];
    const float* Wr1    = (const float*)d_in[7];
    const float* We1    = (const float*)d_in[8];
    const float* att1   = (const float*)d_in[9];
    const float* bo1    = (const float*)d_in[10];
    const float* Wl2    = (const float*)d_in[11];
    const float* bl2    = (const float*)d_in[12];
    const float* Wr2    = (const float*)d_in[13];
    const float* We2    = (const float*)d_in[14];
    const float* att2   = (const float*)d_in[15];
    const float* bo2    = (const float*)d_in[16];
    float* out = (float*)d_out;

    char* p = (char*)d_ws;
    auto carve = [&](size_t bytes) {
        void* q = (void*)p;
        p += (bytes + 255) / 256 * 256;
        return q;
    };
    float* h        = (float*)carve((size_t)HIP_N * 128 * 4);
    float* xl       = (float*)carve((size_t)HIP_N * 128 * 4);
    float* xr       = (float*)carve((size_t)HIP_N * 128 * 4);
    float* ea_s     = (float*)carve((size_t)HIP_E * HIP_ED * 4);
    int*   deg      = (int*)carve((size_t)HIP_N * 4);
    int*   offs     = (int*)carve((size_t)(HIP_N + 1) * 4);
    int*   cursor   = (int*)carve((size_t)HIP_N * 4);
    int*   e_src    = (int*)carve((size_t)HIP_E * 4);
    int*   flag     = (int*)carve(256);
    int*   bsums    = (int*)carve((size_t)SCAN_NB * 4);
    int*   bscan    = (int*)carve((size_t)SCAN_NB * 4);
    float* Wl1f     = (float*)carve(128 * 128 * 4);
    float* Wr1f     = (float*)carve(128 * 128 * 4);
    float* bl1f     = (float*)carve(128 * 4);
    float* br1f     = (float*)carve(128 * 4);
    float* zerob    = (float*)carve(128 * 4);

    hipMemsetAsync(deg, 0, (size_t)HIP_N * 4, stream);
    hipMemsetAsync(flag, 0, 4, stream);

    k_detect<<<16, 256, 0, stream>>>(ei, flag);
    k_hist<<<(HIP_E + 255) / 256, 256, 0, stream>>>(ei, flag, deg);
    k_scan1<<<SCAN_NB, 256, 0, stream>>>(deg, bsums);
    k_scan2<<<1, 64, 0, stream>>>(bsums, bscan);
    k_scan3<<<SCAN_NB, 1024, 0, stream>>>(deg, bscan, offs, cursor);
    k_compose<<<258, 128, 0, stream>>>(W_emb, b_emb, Wl1, bl1, Wr1,
                                       Wl1f, bl1f, Wr1f, br1f, zerob);

    // fat dispatch: layer-1 lin (composed weights, input x) + CSR scatter
    k_fat1<<<LINB + SCATB, 256, 0, stream>>>(x, Wl1f, bl1f, Wr1f, br1f, xl, xr,
                                             ei, flag, cursor, e_src, ea, ea_s);

    // ----- layer 1 -----
    k_node_fused<<<HIP_N, 64, 0, stream>>>(offs, e_src, ea_s, We1, att1,
                                           xl, xr, bo1, h);
    // ----- layer 2 -----
    k_lin<<<(HIP_N + 31) / 32, 256, 0, stream>>>(h, Wl2, bl2, Wr2, zerob, xl, xr, HIP_N);
    k_node_fused<<<HIP_N, 64, 0, stream>>>(offs, e_src, ea_s, We2, att2,
                                           xl, xr, bo2, out);
}